// Round 11
// baseline (173.247 us; speedup 1.0000x reference)
//
#include <hip/hip_runtime.h>
#include <hip/hip_bf16.h>

#define BB 2
#define CC 128
#define HH 48
#define WW 160
#define DD 96
#define HWp (HH*WW)     // 7680
#define CIN 224         // C + D
#define NKC 63          // 2016 / 32 K-chunks
#define H2 50           // HH + 2 (zero halo)
#define W2 162          // WW + 2 (zero halo)
#define PSTR 196        // partialL per-pixel stride in dwords (== 4 mod 32)

typedef __bf16 bf16_t;
typedef __bf16 bf16x8 __attribute__((ext_vector_type(8)));
typedef float  f32x4  __attribute__((ext_vector_type(4)));
typedef float  f32x2  __attribute__((ext_vector_type(2)));

union ABFrag { uint4 u; bf16x8 v; };
union PackW  { bf16_t h[8]; uint4 u; };
union F4     { float4 f; f32x2 h[2]; };
union PK4    { bf16_t h[4]; uint2 u; };

#define CATP_U4 453600   // total uint4's in catP

// ---------------------------------------------------------------------------
// Prep: z = 0,1 -> lookup NCHW->channel-last transpose (batch z);
//       z = 2   -> conv_w pack into MFMA B-fragment order (grid-stride);
//       z = 3   -> zero-fill catP (halo stays zero; k_cost writes interior).
// ---------------------------------------------------------------------------
__global__ __launch_bounds__(256) void k_prep(
    const float* __restrict__ look, const float* __restrict__ cw,
    float* __restrict__ lookT, bf16_t* __restrict__ wPack,
    bf16_t* __restrict__ catP) {
  int z = blockIdx.y;
  if (z < 2) {
    __shared__ float tile[CC * 65];
    int bIdx = z;
    const float* src = look + (size_t)bIdx * CC * HWp;   // F = 1
    int p0 = blockIdx.x * 64;
    int tid = threadIdx.x;
    int px = tid & 63, cb = tid >> 6;
    #pragma unroll
    for (int k = 0; k < 32; k++) {
      int c = k * 4 + cb;
      tile[c * 65 + px] = src[(size_t)c * HWp + p0 + px];
    }
    __syncthreads();
    int ci = tid & 127, pb = tid >> 7;
    #pragma unroll
    for (int k = 0; k < 32; k++) {
      int pp = k * 2 + pb;
      lookT[((size_t)bIdx * HWp + p0 + pp) * CC + ci] = tile[ci * 65 + pp];
    }
  } else if (z == 2) {
    for (int t = blockIdx.x * 256 + threadIdx.x; t < 8 * NKC * 64; t += 120 * 256) {
      int lane = t & 63;
      int kc = (t >> 6) % NKC;
      int nt = t / (NKC * 64);
      int co = nt * 16 + (lane & 15);
      int kbase = kc * 32 + (lane >> 4) * 8;
      PackW tmp;
      #pragma unroll
      for (int j = 0; j < 8; j++) {
        int kk = kbase + j;
        int tap = kk / 224, ci2 = kk % 224;
        int ky = tap / 3, kx = tap % 3;
        tmp.h[j] = (bf16_t)cw[(((size_t)co * 224 + ci2) * 3 + ky) * 3 + kx];
      }
      *(uint4*)(wPack + (size_t)t * 8) = tmp.u;
    }
  } else {
    uint4 zz = make_uint4(0u, 0u, 0u, 0u);
    uint4* cp = (uint4*)catP;
    for (int t = blockIdx.x * 256 + threadIdx.x; t < CATP_U4; t += 120 * 256)
      cp[t] = zz;
  }
}

// ---------------------------------------------------------------------------
// Fused plane-sweep cost, WAVE-INDEPENDENT pixel ownership: each wave owns
// 4 pixels x ALL 96 depths (16 lanes/pixel, 8 ch/lane as two 64-stride
// chunks — each corner-load instruction stays 256B-contiguous). Waves are
// statistically balanced (all see the reload-heavy low-d range), barriers
// amortize over 96 depths, reload bursts halve to 8 loads, corner regs
// halve. Epilogue per depth: 3 shuffles + LDS store of 2 partials; full
// reduction/argmin in phase 2 (deferred, as R10).
// ---------------------------------------------------------------------------
__global__ __launch_bounds__(256) void k_cost(
    const float* __restrict__ cur, const float* __restrict__ lookT,
    const float* __restrict__ poses, const float* __restrict__ Kmat,
    const float* __restrict__ invK,
    bf16_t* __restrict__ catP, float* __restrict__ outLow,
    float* __restrict__ outConf) {
  __shared__ float partialL[16 * PSTR];   // [pixB][d*2 + j]
  __shared__ __align__(4) bf16_t fillL[16 * 96];

  int tid = threadIdx.x;
  int b = blockIdx.y;
  int wv = tid >> 6;
  int lane = tid & 63;
  int pg = lane >> 4;          // pixel-in-wave (4)
  int l = lane & 15;           // 16 lanes per pixel
  int pixB = wv * 4 + pg;      // pixel-in-block (16)
  int p = blockIdx.x * 16 + pixB;
  int hh = p / WW, ww = p % WW;

  const float* Kb  = Kmat + b * 16;
  const float* Tb  = poses + b * 16;   // F = 1
  const float* iKb = invK + b * 16;
  float P[3][4];
  #pragma unroll
  for (int i = 0; i < 3; i++)
    #pragma unroll
    for (int j = 0; j < 4; j++)
      P[i][j] = Kb[i*4+0]*Tb[0*4+j] + Kb[i*4+1]*Tb[1*4+j]
              + Kb[i*4+2]*Tb[2*4+j] + Kb[i*4+3]*Tb[3*4+j];
  float psum = 0.0f;
  #pragma unroll
  for (int i = 0; i < 16; i++) psum += Tb[i];
  bool vpnz = (psum != 0.0f);

  float x = (float)ww, y = (float)hh;
  float cam0 = iKb[0]*x + iKb[1]*y + iKb[2];
  float cam1 = iKb[4]*x + iKb[5]*y + iKb[6];
  float cam2 = iKb[8]*x + iKb[9]*y + iKb[10];
  float qx = P[0][0]*cam0 + P[0][1]*cam1 + P[0][2]*cam2;
  float qy = P[1][0]*cam0 + P[1][1]*cam1 + P[1][2]*cam2;
  float qz = P[2][0]*cam0 + P[2][1]*cam1 + P[2][2]*cam2;
  float px3 = P[0][3], py3 = P[1][3], pz3 = P[2][3];
  bool interior = (hh >= 2 && hh <= HH-3 && ww >= 2 && ww <= WW-3);
  bool groupValid = interior && vpnz;

  // 8 channels/lane: c = l*4 + s4*64 + j (two 64-stride chunks)
  int c0 = l * 4;
  F4 negCur[2];
  #pragma unroll
  for (int s4 = 0; s4 < 2; s4++) {
    float4 t;
    t.x = cur[((size_t)(b * CC + c0 + s4 * 64 + 0)) * HWp + p];
    t.y = cur[((size_t)(b * CC + c0 + s4 * 64 + 1)) * HWp + p];
    t.z = cur[((size_t)(b * CC + c0 + s4 * 64 + 2)) * HWp + p];
    t.w = cur[((size_t)(b * CC + c0 + s4 * 64 + 3)) * HWp + p];
    F4 tt; tt.f = t;
    negCur[s4].h[0] = -tt.h[0];
    negCur[s4].h[1] = -tt.h[1];
  }
  // every wave writes its own pixels' cur channels into catP (bf16)
  bf16_t* pixBase = catP + (((size_t)b * H2 + hh + 1) * W2 + (ww + 1)) * CIN;
  #pragma unroll
  for (int s4 = 0; s4 < 2; s4++) {
    PK4 pk;
    pk.h[0] = (bf16_t)(-negCur[s4].f.x);
    pk.h[1] = (bf16_t)(-negCur[s4].f.y);
    pk.h[2] = (bf16_t)(-negCur[s4].f.z);
    pk.h[3] = (bf16_t)(-negCur[s4].f.w);
    *(uint2*)(pixBase + c0 + s4 * 64) = pk.u;
  }

  const float* lookB = lookT + (size_t)b * HWp * CC;
  const float stepd = (20.0f - 0.1f) / 95.0f;

  int prevCell = -1;
  float x0f = 0.0f, y0f = 0.0f;
  F4 v00[2], v10[2], v01[2], v11[2];
  #pragma unroll
  for (int s4 = 0; s4 < 2; s4++) {
    v00[s4].f = make_float4(0.f,0.f,0.f,0.f);
    v10[s4].f = make_float4(0.f,0.f,0.f,0.f);
    v01[s4].f = make_float4(0.f,0.f,0.f,0.f);
    v11[s4].f = make_float4(0.f,0.f,0.f,0.f);
  }

  for (int d = 0; d < 96; d++) {
    float depth = 0.1f + (float)d * stepd;
    float s = 0.0f;
    if (groupValid) {
      float cxx = fmaf(depth, qx, px3);
      float cyy = fmaf(depth, qy, py3);
      float czz = fmaf(depth, qz, pz3);
      float r = __builtin_amdgcn_rcpf(czz + 1e-7f);
      float gx = cxx * r, gy = cyy * r;
      if (gx >= 2.0f && gx <= (float)(WW-2) && gy >= 2.0f && gy <= (float)(HH-2)) {
        float xf = floorf(gx), yf = floorf(gy);
        int x0 = (int)xf, y0 = (int)yf;
        int cell = y0 * WW + x0;
        if (cell != prevCell) {
          prevCell = cell; x0f = xf; y0f = yf;
          const float* bp0 = lookB + ((size_t)cell * CC + c0);
          const float* bp1 = bp0 + WW * CC;
          #pragma unroll
          for (int s4 = 0; s4 < 2; s4++) {
            v00[s4].f = *(const float4*)(bp0 + s4 * 64);
            v10[s4].f = *(const float4*)(bp0 + s4 * 64 + CC);
            v01[s4].f = *(const float4*)(bp1 + s4 * 64);
            v11[s4].f = *(const float4*)(bp1 + s4 * 64 + CC);
          }
        }
        float wx = gx - x0f, wy = gy - y0f;
        float w11v = wx * wy;
        float w10v = wx - w11v, w01v = wy - w11v;
        float w00v = 1.0f - wx - wy + w11v;
        f32x2 W00 = {w00v, w00v}, W10 = {w10v, w10v};
        f32x2 W01 = {w01v, w01v}, W11 = {w11v, w11v};
        f32x2 accA = {0.f, 0.f}, accB = {0.f, 0.f};
        #pragma unroll
        for (int s4 = 0; s4 < 2; s4++) {
          #pragma unroll
          for (int hf = 0; hf < 2; hf++) {
            f32x2 t = negCur[s4].h[hf];
            t = __builtin_elementwise_fma(W00, v00[s4].h[hf], t);
            t = __builtin_elementwise_fma(W10, v10[s4].h[hf], t);
            t = __builtin_elementwise_fma(W01, v01[s4].h[hf], t);
            t = __builtin_elementwise_fma(W11, v11[s4].h[hf], t);
            f32x2 a = __builtin_elementwise_max(t, -t);
            if (s4 & 1) accB += a; else accA += a;
          }
        }
        f32x2 accT = accA + accB;
        s = accT.x + accT.y;
      }
    }
    // 3 shuffles -> lanes hold 64-ch partials; 2 partials per (pixel,depth)
    s += __shfl_xor(s, 1, 16);
    s += __shfl_xor(s, 2, 16);
    s += __shfl_xor(s, 4, 16);
    if ((l & 7) == 0) partialL[pixB * PSTR + d * 2 + (l >> 3)] = s;
  }
  __syncthreads();

  // phase 2: 16 threads per pixel, 6 depths each — sum partials, scale,
  // max/cnt butterflies, then fill/viz/argmin, write outputs + catP.
  const float kScale = 1.0f / 128.0f / (1.0f + 1e-7f);
  int pix2 = tid >> 4, g = tid & 15;
  int p2 = blockIdx.x * 16 + pix2;
  int hh2 = p2 / WW, ww2 = p2 % WW;
  float c6[6];
  float m0 = 0.0f;
  int ct = 0;
  #pragma unroll
  for (int k = 0; k < 6; k++) {
    int d = g + 16 * k;
    const f32x2 pp = *(const f32x2*)&partialL[pix2 * PSTR + d * 2];
    float c = (pp.x + pp.y) * kScale;
    c6[k] = c;
    m0 = fmaxf(m0, c);
    ct += (c > 0.0f) ? 1 : 0;
  }
  #pragma unroll
  for (int off = 1; off < 16; off <<= 1) {
    m0 = fmaxf(m0, __shfl_xor(m0, off, 16));
    ct += __shfl_xor(ct, off, 16);
  }
  float confF = (ct == DD) ? 1.0f : 0.0f;
  float minv = 3.4e38f;
  int mind = 0x7fffffff;
  #pragma unroll
  for (int k = 0; k < 6; k++) {
    int d = g + 16 * k;
    float c = c6[k];
    float filled = (c == 0.0f) ? m0 : c;
    float viz = (filled == 0.0f) ? 100.0f : filled;
    if (viz < minv) { minv = viz; mind = d; }     // per-thread d ascending
    fillL[pix2 * 96 + d] = (bf16_t)(filled * confF);
  }
  #pragma unroll
  for (int off = 1; off < 16; off <<= 1) {
    float ov = __shfl_xor(minv, off, 16);
    int   oi = __shfl_xor(mind, off, 16);
    if (ov < minv || (ov == minv && oi < mind)) { minv = ov; mind = oi; }
  }
  if (g == 0) {
    outLow[(size_t)b * HWp + p2] = 1.0f / (0.1f + (float)mind * (20.0f - 0.1f) / 95.0f);
    outConf[(size_t)b * HWp + p2] = confF;
  }
  __syncthreads();
  const unsigned* fu = (const unsigned*)fillL;
  unsigned* cu = (unsigned*)(catP + (((size_t)b * H2 + hh2 + 1) * W2 + (ww2 + 1)) * CIN + CC);
  #pragma unroll
  for (int k = 0; k < 3; k++)
    cu[g + 16 * k] = fu[pix2 * 48 + g + 16 * k];
}

// ---------------------------------------------------------------------------
// Implicit-GEMM conv over zero-padded catP (unchanged control). Each wave:
// one 16-pixel tile x 32 out-channels (2 nt); branch-free K-loop. 3840 waves.
// ---------------------------------------------------------------------------
__global__ __launch_bounds__(256) void k_conv(
    const bf16_t* __restrict__ catP, const bf16_t* __restrict__ wPack,
    const float* __restrict__ bias, float* __restrict__ out) {
  int wave = threadIdx.x >> 6;
  int lane = threadIdx.x & 63;
  int m16 = lane & 15, quad = lane >> 4;
  int tile = blockIdx.x * 4 + wave;
  int nt0 = blockIdx.y * 2;
  int P0 = tile * 16;
  int b = P0 / HWp;
  int rp = P0 % HWp;
  int h = rp / WW, w0 = rp % WW;

  f32x4 acc[2];
  #pragma unroll
  for (int j = 0; j < 2; j++) { f32x4 z = {0.f,0.f,0.f,0.f}; acc[j] = z; }

  #pragma unroll
  for (int tap = 0; tap < 9; tap++) {
    int dy = tap / 3 - 1, dx = tap % 3 - 1;
    const bf16_t* ap = catP
      + ((size_t)(b * H2 + h + dy + 1) * W2 + (w0 + m16 + dx + 1)) * CIN
      + quad * 8;
    #pragma unroll
    for (int sub = 0; sub < 7; sub++) {
      ABFrag a;
      a.u = *(const uint4*)(ap + sub * 32);
      int kc = tap * 7 + sub;
      #pragma unroll
      for (int j = 0; j < 2; j++) {
        ABFrag bb;
        bb.u = *(const uint4*)(wPack + (((size_t)(nt0 + j) * NKC + kc) * 64 + lane) * 8);
        acc[j] = __builtin_amdgcn_mfma_f32_16x16x32_bf16(a.v, bb.v, acc[j], 0, 0, 0);
      }
    }
  }
  // C/D layout: n = lane&15, m = quad*4 + r
  #pragma unroll
  for (int j = 0; j < 2; j++) {
    int co = (nt0 + j) * 16 + m16;
    float bi = bias[co];
    #pragma unroll
    for (int r = 0; r < 4; r++) {
      int wloc = w0 + quad * 4 + r;
      float v = acc[j][r] + bi;
      v = v > 0.0f ? v : 0.0f;
      out[(((size_t)b * CC + co) * HH + h) * WW + wloc] = v;
    }
  }
}

// ---------------------------------------------------------------------------
extern "C" void kernel_launch(void* const* d_in, const int* in_sizes, int n_in,
                              void* d_out, int out_size, void* d_ws, size_t ws_size,
                              hipStream_t stream) {
  const float* cur   = (const float*)d_in[0];
  const float* look  = (const float*)d_in[1];
  const float* poses = (const float*)d_in[2];
  const float* Km    = (const float*)d_in[3];
  const float* iK    = (const float*)d_in[4];
  const float* cw    = (const float*)d_in[5];
  const float* cb    = (const float*)d_in[6];

  float* out     = (float*)d_out;
  float* outLow  = out + (size_t)BB * CC * HWp;
  float* outConf = outLow + (size_t)BB * HWp;

  char* ws = (char*)d_ws;
  float*  lookT = (float*)ws;                                   // 7,864,320 B
  bf16_t* catP  = (bf16_t*)(ws + 7864320);                      // 7,257,600 B
  bf16_t* wPack = (bf16_t*)(ws + 7864320 + 7257600);            //   516,096 B

  k_prep<<<dim3(120, 4), 256, 0, stream>>>(look, cw, lookT, wPack, catP);
  k_cost<<<dim3(480, 2), 256, 0, stream>>>(cur, lookT, poses, Km, iK,
                                           catP, outLow, outConf);
  k_conv<<<dim3(240, 4), 256, 0, stream>>>(catP, wPack, cb, out);
}

// Round 12
// 153.428 us; speedup vs baseline: 1.1292x; 1.1292x over previous
//
#include <hip/hip_runtime.h>
#include <hip/hip_bf16.h>

#define BB 2
#define CC 128
#define HH 48
#define WW 160
#define DD 96
#define HWp (HH*WW)     // 7680
#define CIN 224         // C + D
#define NKC 63          // 2016 / 32 K-chunks
#define H2 50           // HH + 2 (zero halo)
#define W2 162          // WW + 2 (zero halo)
#define PSTR 392        // partialL per-pixel stride in dwords (== 8 mod 32)

typedef __bf16 bf16_t;
typedef __bf16 bf16x8 __attribute__((ext_vector_type(8)));
typedef float  f32x4  __attribute__((ext_vector_type(4)));
typedef float  f32x2  __attribute__((ext_vector_type(2)));

union ABFrag { uint4 u; bf16x8 v; };
union PackW  { bf16_t h[8]; uint4 u; };
union F4     { float4 f; f32x2 h[2]; };
union PK4    { bf16_t h[4]; uint2 u; };

#define CATP_U4 453600   // total uint4's in catP

// ---------------------------------------------------------------------------
// Prep: z = 0,1 -> lookup NCHW->channel-last transpose (batch z);
//       z = 2   -> conv_w pack into MFMA B-fragment order (grid-stride);
//       z = 3   -> zero-fill catP (halo stays zero; k_cost writes interior).
// ---------------------------------------------------------------------------
__global__ __launch_bounds__(256) void k_prep(
    const float* __restrict__ look, const float* __restrict__ cw,
    float* __restrict__ lookT, bf16_t* __restrict__ wPack,
    bf16_t* __restrict__ catP) {
  int z = blockIdx.y;
  if (z < 2) {
    __shared__ float tile[CC * 65];
    int bIdx = z;
    const float* src = look + (size_t)bIdx * CC * HWp;   // F = 1
    int p0 = blockIdx.x * 64;
    int tid = threadIdx.x;
    int px = tid & 63, cb = tid >> 6;
    #pragma unroll
    for (int k = 0; k < 32; k++) {
      int c = k * 4 + cb;
      tile[c * 65 + px] = src[(size_t)c * HWp + p0 + px];
    }
    __syncthreads();
    int ci = tid & 127, pb = tid >> 7;
    #pragma unroll
    for (int k = 0; k < 32; k++) {
      int pp = k * 2 + pb;
      lookT[((size_t)bIdx * HWp + p0 + pp) * CC + ci] = tile[ci * 65 + pp];
    }
  } else if (z == 2) {
    for (int t = blockIdx.x * 256 + threadIdx.x; t < 8 * NKC * 64; t += 120 * 256) {
      int lane = t & 63;
      int kc = (t >> 6) % NKC;
      int nt = t / (NKC * 64);
      int co = nt * 16 + (lane & 15);
      int kbase = kc * 32 + (lane >> 4) * 8;
      PackW tmp;
      #pragma unroll
      for (int j = 0; j < 8; j++) {
        int kk = kbase + j;
        int tap = kk / 224, ci2 = kk % 224;
        int ky = tap / 3, kx = tap % 3;
        tmp.h[j] = (bf16_t)cw[(((size_t)co * 224 + ci2) * 3 + ky) * 3 + kx];
      }
      *(uint4*)(wPack + (size_t)t * 8) = tmp.u;
    }
  } else {
    uint4 zz = make_uint4(0u, 0u, 0u, 0u);
    uint4* cp = (uint4*)catP;
    for (int t = blockIdx.x * 256 + threadIdx.x; t < CATP_U4; t += 120 * 256)
      cp[t] = zz;
  }
}

// ---------------------------------------------------------------------------
// Fused plane-sweep cost (R10 structure — measured optimum). Phase 1: blend
// only; per depth the epilogue is ONE pair-shuffle + one LDS store of 4
// partials. Block = 4 waves over the SAME 8 pixels; wave wv covers depths
// [wv*24, wv*24+24); 8 lanes/pixel, 16 ch/lane, depth-coherent corner
// reuse, packed-fp32 math. Full reduction/argmin deferred to phase 2.
// ---------------------------------------------------------------------------
__global__ __launch_bounds__(256) void k_cost(
    const float* __restrict__ cur, const float* __restrict__ lookT,
    const float* __restrict__ poses, const float* __restrict__ Kmat,
    const float* __restrict__ invK,
    bf16_t* __restrict__ catP, float* __restrict__ outLow,
    float* __restrict__ outConf) {
  __shared__ float partialL[8 * PSTR];   // [pix][d*4 + j], 2-way-conflict-free
  __shared__ __align__(4) bf16_t fillL[8 * 96];

  int tid = threadIdx.x;
  int b = blockIdx.y;
  int wv = tid >> 6;
  int lane = tid & 63;
  int pix = lane >> 3;
  int l = lane & 7;
  int p = blockIdx.x * 8 + pix;
  int hh = p / WW, ww = p % WW;

  const float* Kb  = Kmat + b * 16;
  const float* Tb  = poses + b * 16;   // F = 1
  const float* iKb = invK + b * 16;
  float P[3][4];
  #pragma unroll
  for (int i = 0; i < 3; i++)
    #pragma unroll
    for (int j = 0; j < 4; j++)
      P[i][j] = Kb[i*4+0]*Tb[0*4+j] + Kb[i*4+1]*Tb[1*4+j]
              + Kb[i*4+2]*Tb[2*4+j] + Kb[i*4+3]*Tb[3*4+j];
  float psum = 0.0f;
  #pragma unroll
  for (int i = 0; i < 16; i++) psum += Tb[i];
  bool vpnz = (psum != 0.0f);

  float x = (float)ww, y = (float)hh;
  float cam0 = iKb[0]*x + iKb[1]*y + iKb[2];
  float cam1 = iKb[4]*x + iKb[5]*y + iKb[6];
  float cam2 = iKb[8]*x + iKb[9]*y + iKb[10];
  float qx = P[0][0]*cam0 + P[0][1]*cam1 + P[0][2]*cam2;
  float qy = P[1][0]*cam0 + P[1][1]*cam1 + P[1][2]*cam2;
  float qz = P[2][0]*cam0 + P[2][1]*cam1 + P[2][2]*cam2;
  float px3 = P[0][3], py3 = P[1][3], pz3 = P[2][3];
  bool interior = (hh >= 2 && hh <= HH-3 && ww >= 2 && ww <= WW-3);
  bool groupValid = interior && vpnz;

  // current features straight from NCHW (16 scalar loads, once per wave)
  int l4 = l * 4;
  F4 negCur[4];
  #pragma unroll
  for (int s4 = 0; s4 < 4; s4++) {
    float4 t;
    t.x = cur[((size_t)(b * CC + l4 + s4 * 32 + 0)) * HWp + p];
    t.y = cur[((size_t)(b * CC + l4 + s4 * 32 + 1)) * HWp + p];
    t.z = cur[((size_t)(b * CC + l4 + s4 * 32 + 2)) * HWp + p];
    t.w = cur[((size_t)(b * CC + l4 + s4 * 32 + 3)) * HWp + p];
    F4 tt; tt.f = t;
    negCur[s4].h[0] = -tt.h[0];
    negCur[s4].h[1] = -tt.h[1];
  }
  // wave 0 writes catP's cur channels (bf16), padded addressing
  bf16_t* pixBase = catP + (((size_t)b * H2 + hh + 1) * W2 + (ww + 1)) * CIN;
  if (wv == 0) {
    #pragma unroll
    for (int s4 = 0; s4 < 4; s4++) {
      PK4 pk;
      pk.h[0] = (bf16_t)(-negCur[s4].f.x);
      pk.h[1] = (bf16_t)(-negCur[s4].f.y);
      pk.h[2] = (bf16_t)(-negCur[s4].f.z);
      pk.h[3] = (bf16_t)(-negCur[s4].f.w);
      *(uint2*)(pixBase + l4 + s4 * 32) = pk.u;
    }
  }

  const float* lookB = lookT + (size_t)b * HWp * CC;
  const float stepd = (20.0f - 0.1f) / 95.0f;

  int prevCell = -1;
  float x0f = 0.0f, y0f = 0.0f;
  F4 v00[4], v10[4], v01[4], v11[4];
  #pragma unroll
  for (int s4 = 0; s4 < 4; s4++) {
    v00[s4].f = make_float4(0.f,0.f,0.f,0.f);
    v10[s4].f = make_float4(0.f,0.f,0.f,0.f);
    v01[s4].f = make_float4(0.f,0.f,0.f,0.f);
    v11[s4].f = make_float4(0.f,0.f,0.f,0.f);
  }

  for (int dd = 0; dd < 24; dd++) {
    int d = wv * 24 + dd;
    float depth = 0.1f + (float)d * stepd;
    float s = 0.0f;
    if (groupValid) {
      float cxx = fmaf(depth, qx, px3);
      float cyy = fmaf(depth, qy, py3);
      float czz = fmaf(depth, qz, pz3);
      float r = __builtin_amdgcn_rcpf(czz + 1e-7f);
      float gx = cxx * r, gy = cyy * r;
      if (gx >= 2.0f && gx <= (float)(WW-2) && gy >= 2.0f && gy <= (float)(HH-2)) {
        float xf = floorf(gx), yf = floorf(gy);
        int x0 = (int)xf, y0 = (int)yf;
        int cell = y0 * WW + x0;
        if (cell != prevCell) {
          prevCell = cell; x0f = xf; y0f = yf;
          const float* bp0 = lookB + ((size_t)cell * CC + l4);
          const float* bp1 = bp0 + WW * CC;
          #pragma unroll
          for (int s4 = 0; s4 < 4; s4++) {
            v00[s4].f = *(const float4*)(bp0 + s4 * 32);
            v10[s4].f = *(const float4*)(bp0 + s4 * 32 + CC);
            v01[s4].f = *(const float4*)(bp1 + s4 * 32);
            v11[s4].f = *(const float4*)(bp1 + s4 * 32 + CC);
          }
        }
        float wx = gx - x0f, wy = gy - y0f;
        float w11v = wx * wy;
        float w10v = wx - w11v, w01v = wy - w11v;
        float w00v = 1.0f - wx - wy + w11v;
        f32x2 W00 = {w00v, w00v}, W10 = {w10v, w10v};
        f32x2 W01 = {w01v, w01v}, W11 = {w11v, w11v};
        f32x2 accA = {0.f, 0.f}, accB = {0.f, 0.f};
        #pragma unroll
        for (int s4 = 0; s4 < 4; s4++) {
          #pragma unroll
          for (int hf = 0; hf < 2; hf++) {
            f32x2 t = negCur[s4].h[hf];
            t = __builtin_elementwise_fma(W00, v00[s4].h[hf], t);
            t = __builtin_elementwise_fma(W10, v10[s4].h[hf], t);
            t = __builtin_elementwise_fma(W01, v01[s4].h[hf], t);
            t = __builtin_elementwise_fma(W11, v11[s4].h[hf], t);
            f32x2 a = __builtin_elementwise_max(t, -t);
            if (s4 & 1) accB += a; else accA += a;
          }
        }
        f32x2 accT = accA + accB;
        s = accT.x + accT.y;
      }
    }
    // pair-sum + store 4 partials; full reduction deferred to phase 2
    s += __shfl_xor(s, 1, 8);
    if ((l & 1) == 0) partialL[pix * PSTR + d * 4 + (l >> 1)] = s;
  }
  __syncthreads();

  // phase 2: 32 threads per pixel, 3 depths each — sum partials, scale,
  // max/cnt butterflies, then fill/viz/argmin, write outputs + catP.
  const float kScale = 1.0f / 128.0f / (1.0f + 1e-7f);
  int pix2 = tid >> 5, g = tid & 31;
  int p2 = blockIdx.x * 8 + pix2;
  int hh2 = p2 / WW, ww2 = p2 % WW;
  float c3[3];
  float m0 = 0.0f;
  int ct = 0;
  #pragma unroll
  for (int k = 0; k < 3; k++) {
    int d = g + 32 * k;
    const float4 pp = *(const float4*)&partialL[pix2 * PSTR + d * 4];
    float c = ((pp.x + pp.y) + (pp.z + pp.w)) * kScale;
    c3[k] = c;
    m0 = fmaxf(m0, c);
    ct += (c > 0.0f) ? 1 : 0;
  }
  #pragma unroll
  for (int off = 1; off < 32; off <<= 1) {
    m0 = fmaxf(m0, __shfl_xor(m0, off, 32));
    ct += __shfl_xor(ct, off, 32);
  }
  float confF = (ct == DD) ? 1.0f : 0.0f;
  float minv = 3.4e38f;
  int mind = 0x7fffffff;
  #pragma unroll
  for (int k = 0; k < 3; k++) {
    int d = g + 32 * k;
    float c = c3[k];
    float filled = (c == 0.0f) ? m0 : c;
    float viz = (filled == 0.0f) ? 100.0f : filled;
    if (viz < minv) { minv = viz; mind = d; }     // per-thread d ascending
    fillL[pix2 * 96 + d] = (bf16_t)(filled * confF);
  }
  #pragma unroll
  for (int off = 1; off < 32; off <<= 1) {
    float ov = __shfl_xor(minv, off, 32);
    int   oi = __shfl_xor(mind, off, 32);
    if (ov < minv || (ov == minv && oi < mind)) { minv = ov; mind = oi; }
  }
  if (g == 0) {
    outLow[(size_t)b * HWp + p2] = 1.0f / (0.1f + (float)mind * (20.0f - 0.1f) / 95.0f);
    outConf[(size_t)b * HWp + p2] = confF;
  }
  __syncthreads();
  const unsigned* fu = (const unsigned*)fillL;
  unsigned* cu = (unsigned*)(catP + (((size_t)b * H2 + hh2 + 1) * W2 + (ww2 + 1)) * CIN + CC);
  #pragma unroll
  for (int k = 0; k < 2; k++) {
    int idx = g + 32 * k;
    if (idx < 48) cu[idx] = fu[pix2 * 48 + idx];
  }
}

// ---------------------------------------------------------------------------
// Implicit-GEMM conv over zero-padded catP (unchanged control). Each wave:
// one 16-pixel tile x 32 out-channels (2 nt); branch-free K-loop. 3840 waves.
// ---------------------------------------------------------------------------
__global__ __launch_bounds__(256) void k_conv(
    const bf16_t* __restrict__ catP, const bf16_t* __restrict__ wPack,
    const float* __restrict__ bias, float* __restrict__ out) {
  int wave = threadIdx.x >> 6;
  int lane = threadIdx.x & 63;
  int m16 = lane & 15, quad = lane >> 4;
  int tile = blockIdx.x * 4 + wave;
  int nt0 = blockIdx.y * 2;
  int P0 = tile * 16;
  int b = P0 / HWp;
  int rp = P0 % HWp;
  int h = rp / WW, w0 = rp % WW;

  f32x4 acc[2];
  #pragma unroll
  for (int j = 0; j < 2; j++) { f32x4 z = {0.f,0.f,0.f,0.f}; acc[j] = z; }

  #pragma unroll
  for (int tap = 0; tap < 9; tap++) {
    int dy = tap / 3 - 1, dx = tap % 3 - 1;
    const bf16_t* ap = catP
      + ((size_t)(b * H2 + h + dy + 1) * W2 + (w0 + m16 + dx + 1)) * CIN
      + quad * 8;
    #pragma unroll
    for (int sub = 0; sub < 7; sub++) {
      ABFrag a;
      a.u = *(const uint4*)(ap + sub * 32);
      int kc = tap * 7 + sub;
      #pragma unroll
      for (int j = 0; j < 2; j++) {
        ABFrag bb;
        bb.u = *(const uint4*)(wPack + (((size_t)(nt0 + j) * NKC + kc) * 64 + lane) * 8);
        acc[j] = __builtin_amdgcn_mfma_f32_16x16x32_bf16(a.v, bb.v, acc[j], 0, 0, 0);
      }
    }
  }
  // C/D layout: n = lane&15, m = quad*4 + r
  #pragma unroll
  for (int j = 0; j < 2; j++) {
    int co = (nt0 + j) * 16 + m16;
    float bi = bias[co];
    #pragma unroll
    for (int r = 0; r < 4; r++) {
      int wloc = w0 + quad * 4 + r;
      float v = acc[j][r] + bi;
      v = v > 0.0f ? v : 0.0f;
      out[(((size_t)b * CC + co) * HH + h) * WW + wloc] = v;
    }
  }
}

// ---------------------------------------------------------------------------
extern "C" void kernel_launch(void* const* d_in, const int* in_sizes, int n_in,
                              void* d_out, int out_size, void* d_ws, size_t ws_size,
                              hipStream_t stream) {
  const float* cur   = (const float*)d_in[0];
  const float* look  = (const float*)d_in[1];
  const float* poses = (const float*)d_in[2];
  const float* Km    = (const float*)d_in[3];
  const float* iK    = (const float*)d_in[4];
  const float* cw    = (const float*)d_in[5];
  const float* cb    = (const float*)d_in[6];

  float* out     = (float*)d_out;
  float* outLow  = out + (size_t)BB * CC * HWp;
  float* outConf = outLow + (size_t)BB * HWp;

  char* ws = (char*)d_ws;
  float*  lookT = (float*)ws;                                   // 7,864,320 B
  bf16_t* catP  = (bf16_t*)(ws + 7864320);                      // 7,257,600 B
  bf16_t* wPack = (bf16_t*)(ws + 7864320 + 7257600);            //   516,096 B

  k_prep<<<dim3(120, 4), 256, 0, stream>>>(look, cw, lookT, wPack, catP);
  k_cost<<<dim3(960, 2), 256, 0, stream>>>(cur, lookT, poses, Km, iK,
                                           catP, outLow, outConf);
  k_conv<<<dim3(240, 4), 256, 0, stream>>>(catP, wPack, cb, out);
}